// Round 2
// baseline (99.329 us; speedup 1.0000x reference)
//
#include <hip/hip_runtime.h>
#include <hip/hip_bf16.h>

// EntityRepr: gather spans -> mention means -> entity means + mask.
// B=32, L=512, H=768, E=32, M=8, S=4.
// Outputs concatenated fp32: entity [B,E,H] | mentions [B,E,M,H] | mask [B,E,M].
//
// Round 1 -> 2: split into two kernels for TLP. Round-1 single kernel had
// only 12 waves/CU and was gather-latency-bound (97 us vs ~13 us roofline).
// Kernel A: one block per (b,e,m) -> 96 waves/CU over the random gathers.
// Kernel B: streaming reduce over mention means (LLC-hot) + mask.

#define B_  32
#define L_  512
#define H_  768
#define E_  32
#define M_  8
#define S_  4
#define H4_ (H_ / 4)              // 192 float4 per H-vector

#define ENT_ELEMS   (B_ * E_ * H_)          // 786432
#define MEN_ELEMS   (B_ * E_ * M_ * H_)     // 6291456
#define MEN_OFFSET  ENT_ELEMS               // 786432
#define MASK_OFFSET (ENT_ELEMS + MEN_ELEMS) // 7077888

// ---- Kernel A: mention means -------------------------------------------
// grid = B*E*M = 8192 blocks, block = 192 threads (one float4 column each).
__global__ __launch_bounds__(H4_) void mention_kernel(
    const float* __restrict__ tok,   // [B, L, H]
    const int*   __restrict__ idx,   // [B, E, M, S]
    float*       __restrict__ out)
{
    const int bem = blockIdx.x;          // (b*E + e)*M + m
    const int be  = bem >> 3;            // /M_
    const int b   = be >> 5;             // /E_
    const int t   = threadIdx.x;         // 0..191

    const float4* tb = (const float4*)(tok) + (size_t)b * L_ * H4_;
    const int*    ip = idx + (size_t)bem * S_;

    const int i0 = ip[0];
    const int i1 = ip[1];
    const int i2 = ip[2];
    const int i3 = ip[3];

    const float4 a = tb[(size_t)i0 * H4_ + t];
    const float4 c = tb[(size_t)i1 * H4_ + t];
    const float4 d = tb[(size_t)i2 * H4_ + t];
    const float4 e = tb[(size_t)i3 * H4_ + t];

    float4 mn;
    mn.x = (a.x + c.x + d.x + e.x) * 0.25f;
    mn.y = (a.y + c.y + d.y + e.y) * 0.25f;
    mn.z = (a.z + c.z + d.z + e.z) * 0.25f;
    mn.w = (a.w + c.w + d.w + e.w) * 0.25f;

    ((float4*)(out + MEN_OFFSET))[(size_t)bem * H4_ + t] = mn;
}

// ---- Kernel B: entity means + mask -------------------------------------
// grid = B*E = 1024 blocks, block = 192 threads.
__global__ __launch_bounds__(H4_) void entity_kernel(
    float* __restrict__ out)
{
    const int be = blockIdx.x;           // b*E + e
    const int t  = threadIdx.x;          // 0..191

    const float4* men = (const float4*)(out + MEN_OFFSET) + (size_t)be * (M_ * H4_);

    float ex = 0.f, ey = 0.f, ez = 0.f, ew = 0.f;
    #pragma unroll
    for (int m = 0; m < M_; ++m) {
        const float4 mn = men[(size_t)m * H4_ + t];
        ex += mn.x; ey += mn.y; ez += mn.z; ew += mn.w;
    }

    float4 ev;
    ev.x = ex * (1.0f / M_);
    ev.y = ey * (1.0f / M_);
    ev.z = ez * (1.0f / M_);
    ev.w = ew * (1.0f / M_);
    ((float4*)(out))[(size_t)be * H4_ + t] = ev;

    if (t < M_) {
        out[MASK_OFFSET + (size_t)be * M_ + t] = 1.0f;
    }
}

extern "C" void kernel_launch(void* const* d_in, const int* in_sizes, int n_in,
                              void* d_out, int out_size, void* d_ws, size_t ws_size,
                              hipStream_t stream) {
    const float* tok = (const float*)d_in[0];
    const int*   idx = (const int*)d_in[1];
    float*       out = (float*)d_out;

    mention_kernel<<<dim3(B_ * E_ * M_), dim3(H4_), 0, stream>>>(tok, idx, out);
    entity_kernel <<<dim3(B_ * E_),      dim3(H4_), 0, stream>>>(out);
}

// Round 4
// 94.100 us; speedup vs baseline: 1.0556x; 1.0556x over previous
//
#include <hip/hip_runtime.h>
#include <hip/hip_bf16.h>

// EntityRepr: gather spans -> mention means -> entity means + mask.
// B=32, L=512, H=768, E=32, M=8, S=4.
// Outputs concatenated fp32: entity [B,E,H] | mentions [B,E,M,H] | mask [B,E,M].
//
// Round 3 -> 4: same design as round 3 (fused, 768-thread blocks, XCD-aware
// swizzle, non-temporal stores) but using a clang ext_vector_type float4
// (v4f) — __builtin_nontemporal_store rejects HIP_vector_type<float,4>.

#define B_  32
#define L_  512
#define H_  768
#define E_  32
#define M_  8
#define S_  4
#define H4_ (H_ / 4)              // 192 float4 per H-vector

#define ENT_ELEMS   (B_ * E_ * H_)          // 786432
#define MEN_ELEMS   (B_ * E_ * M_ * H_)     // 6291456
#define MEN_OFFSET  ENT_ELEMS               // 786432
#define MASK_OFFSET (ENT_ELEMS + MEN_ELEMS) // 7077888

typedef float v4f __attribute__((ext_vector_type(4)));

__global__ __launch_bounds__(768) void entity_repr_fused(
    const float* __restrict__ tok,   // [B, L, H]
    const int*   __restrict__ idx,   // [B, E, M, S]
    float*       __restrict__ out)
{
    // XCD swizzle: consecutive blockIdx round-robins over the 8 XCDs, so
    // put blocks whose linear index is congruent mod 8 (-> same XCD) on the
    // same group of batches: XCD k handles batches {k, k+8, k+16, k+24},
    // sequentially in time (32 consecutive j-slots per batch). Per-batch
    // token table is 1.5 MB -> fits the 4 MB per-XCD L2.
    const int s   = blockIdx.x;          // 0..1023
    const int xcd = s & 7;
    const int j   = s >> 3;              // 0..127
    const int b   = xcd + 8 * (j >> 5);  // batch
    const int e   = j & 31;              // entity
    const int be  = b * E_ + e;

    const int t    = threadIdx.x;        // 0..767
    const int mgrp = t / 192;            // 0..3 (mention group)
    const int col  = t - mgrp * 192;     // 0..191 (float4 column)

    const v4f* tb = (const v4f*)(tok) + (size_t)b * L_ * H4_;
    const int* ip = idx + (size_t)be * (M_ * S_);

    v4f* men_out = (v4f*)(out + MEN_OFFSET) + (size_t)be * (M_ * H4_);

    v4f acc = (v4f)(0.f);

    #pragma unroll
    for (int mm = 0; mm < 2; ++mm) {
        const int m  = mgrp + mm * 4;
        const int i0 = ip[m * S_ + 0];
        const int i1 = ip[m * S_ + 1];
        const int i2 = ip[m * S_ + 2];
        const int i3 = ip[m * S_ + 3];

        const v4f g0 = tb[(size_t)i0 * H4_ + col];
        const v4f g1 = tb[(size_t)i1 * H4_ + col];
        const v4f g2 = tb[(size_t)i2 * H4_ + col];
        const v4f g3 = tb[(size_t)i3 * H4_ + col];

        const v4f mn = (g0 + g1 + g2 + g3) * 0.25f;

        __builtin_nontemporal_store(mn, &men_out[(size_t)m * H4_ + col]);

        acc += mn;
    }

    // Block reduce across the 4 mention groups per column.
    __shared__ v4f red[4][H4_];          // 12 KB
    red[mgrp][col] = acc;
    __syncthreads();

    if (mgrp == 0) {
        const v4f r = (red[0][col] + red[1][col] + red[2][col] + red[3][col])
                      * (1.0f / M_);
        __builtin_nontemporal_store(r, &((v4f*)out)[(size_t)be * H4_ + col]);
    }

    if (t < M_) {
        __builtin_nontemporal_store(1.0f, &out[MASK_OFFSET + (size_t)be * M_ + t]);
    }
}

extern "C" void kernel_launch(void* const* d_in, const int* in_sizes, int n_in,
                              void* d_out, int out_size, void* d_ws, size_t ws_size,
                              hipStream_t stream) {
    const float* tok = (const float*)d_in[0];
    const int*   idx = (const int*)d_in[1];
    float*       out = (float*)d_out;

    entity_repr_fused<<<dim3(B_ * E_), dim3(768), 0, stream>>>(tok, idx, out);
}